// Round 1
// baseline (227.212 us; speedup 1.0000x reference)
//
#include <hip/hip_runtime.h>
#include <math.h>

// DetectionLayer: per cell (b, gy, gx) of a 28x28 grid with 105 channels:
//   ch 0..24  = 5 anchors x [x,y,w,h,conf]  -> sigmoid
//   ch 25..104 = 80 class logits            -> softmax
// Outputs (concatenated flat in d_out, all f32):
//   b_pred_loc [B, 3920, 4]   (xyxy boxes)
//   b_cls      [B, 3920, 80]  (softmax * conf)
//   b_conf     [B, 3920]
//
// One 64-lane wave per cell. 4 waves / 256-thread block.

__global__ __launch_bounds__(256) void det_kernel(
    const float* __restrict__ in, float* __restrict__ out,
    int total_cells, size_t cls_off, size_t conf_off)
{
    const int wave = blockIdx.x * (blockDim.x >> 6) + (threadIdx.x >> 6);
    const int lane = threadIdx.x & 63;
    if (wave >= total_cells) return;

    const float* __restrict__ xp = in + (size_t)wave * 105;

    // ---- loads (contiguous, each element exactly once) ----
    float lc = (lane < 25) ? xp[lane] : 0.0f;          // loc/conf channels 0..24
    float c0 = xp[25 + lane];                          // class logits 0..63
    float c1 = (lane < 16) ? xp[89 + lane] : -INFINITY; // class logits 64..79

    // ---- sigmoid on loc/conf ----
    float slc = 1.0f / (1.0f + __expf(-lc));

    // ---- softmax over 80 classes (wave reduce) ----
    float m = fmaxf(c0, c1);
    #pragma unroll
    for (int off = 32; off >= 1; off >>= 1)
        m = fmaxf(m, __shfl_xor(m, off));
    float e0 = __expf(c0 - m);
    float e1 = (lane < 16) ? __expf(c1 - m) : 0.0f;
    float s = e0 + e1;
    #pragma unroll
    for (int off = 32; off >= 1; off >>= 1)
        s += __shfl_xor(s, off);
    float inv = 1.0f / s;
    float p0 = e0 * inv;
    float p1 = e1 * inv;

    // ---- broadcast the 5 anchor confidences (sigmoid of ch n*5+4) ----
    float conf0 = __shfl(slc, 4);
    float conf1 = __shfl(slc, 9);
    float conf2 = __shfl(slc, 14);
    float conf3 = __shfl(slc, 19);
    float conf4 = __shfl(slc, 24);

    // ---- b_cls: 400 contiguous floats per cell ----
    float* __restrict__ cls = out + cls_off + (size_t)wave * 400;
    cls[  0 + lane] = p0 * conf0;
    cls[ 80 + lane] = p0 * conf1;
    cls[160 + lane] = p0 * conf2;
    cls[240 + lane] = p0 * conf3;
    cls[320 + lane] = p0 * conf4;
    if (lane < 16) {
        cls[ 64 + lane] = p1 * conf0;
        cls[144 + lane] = p1 * conf1;
        cls[224 + lane] = p1 * conf2;
        cls[304 + lane] = p1 * conf3;
        cls[384 + lane] = p1 * conf4;
    }

    // ---- b_conf: lanes 4,9,14,19,24 hold the conf sigmoids ----
    if (lane < 25 && (lane % 5) == 4)
        out[conf_off + (size_t)wave * 5 + (lane / 5)] = slc;

    // ---- b_pred_loc: 5 anchors, one float4 per anchor from lanes 0..4 ----
    int nl = (lane < 5) ? lane : 0;             // keep shfl src in range
    float sx = __shfl(slc, nl * 5 + 0);
    float sy = __shfl(slc, nl * 5 + 1);
    float sw = __shfl(slc, nl * 5 + 2);
    float sh = __shfl(slc, nl * 5 + 3);
    if (lane < 5) {
        int cell = wave % 784;                  // cell = gy*28 + gx
        float gx = (float)(cell % 28);
        float gy = (float)(cell / 28);
        const float invS = 1.0f / 28.0f;
        float px = (sx + gx) * invS;
        float py = (sy + gy) * invS;
        float hw = sw * 0.5f;
        float hh = sh * 0.5f;
        float4 box = make_float4(px - hw, py - hh, px + hw, py + hh);
        *reinterpret_cast<float4*>(out + ((size_t)wave * 5 + lane) * 4) = box;
    }
}

extern "C" void kernel_launch(void* const* d_in, const int* in_sizes, int n_in,
                              void* d_out, int out_size, void* d_ws, size_t ws_size,
                              hipStream_t stream) {
    const float* in = (const float*)d_in[0];
    float* out = (float*)d_out;

    const size_t total_cells = (size_t)in_sizes[0] / 105;   // B * 784
    const size_t anchors     = total_cells * 5;
    const size_t cls_off     = anchors * 4;                 // after b_pred_loc
    const size_t conf_off    = cls_off + anchors * 80;      // after b_cls

    const int waves_per_block = 4;                          // 256 threads
    const int blocks = (int)((total_cells + waves_per_block - 1) / waves_per_block);

    det_kernel<<<blocks, 256, 0, stream>>>(in, out, (int)total_cells,
                                           cls_off, conf_off);
}